// Round 1
// baseline (274.897 us; speedup 1.0000x reference)
//
#include <hip/hip_runtime.h>
#include <cstdint>
#include <cstddef>

// LocallyDirected1D: y[b,o] = tanh( sum_{e: out_idx[e]==o} x[b, in_idx[e]] * w[e] + bias[o] )
// out_idx is sorted ascending. lane <-> batch (B == 64 == wave size).
// Each wave owns OPW consecutive outputs; its edge range [E0,E1) is found by
// block-parallel binary search. x reads are contiguous per lane (in_idx is a
// range in practice; verified per 4-group with scalar fallback).

constexpr int WAVES_PER_BLOCK = 4;
constexpr int OPW = 4; // outputs per wave

__global__ __launch_bounds__(256)
void LocallyDirected1D_kernel(const float* __restrict__ x,
                              const float* __restrict__ wgt,
                              const float* __restrict__ bias,
                              const int*   __restrict__ in_idx,
                              const int*   __restrict__ out_idx,
                              float*       __restrict__ out,
                              int n_in, int nnz, int n_out, int batch)
{
    const int lane = threadIdx.x & 63;
    const int wib  = threadIdx.x >> 6;
    const int wave = blockIdx.x * WAVES_PER_BLOCK + wib;

    // Block-parallel lower_bound searches for the 5 wave-range boundaries.
    __shared__ int sbound[WAVES_PER_BLOCK + 1];
    if (threadIdx.x <= WAVES_PER_BLOCK) {
        int ob = (blockIdx.x * WAVES_PER_BLOCK + (int)threadIdx.x) * OPW;
        if (ob > n_out) ob = n_out;
        int lo = 0, hi = nnz;
        while (lo < hi) {
            int mid = (lo + hi) >> 1;
            if (out_idx[mid] < ob) lo = mid + 1; else hi = mid;
        }
        sbound[threadIdx.x] = lo;
    }
    __syncthreads();

    const int o_begin = wave * OPW;
    if (o_begin >= n_out) return;
    const int o_end = min(o_begin + OPW, n_out);

    int e        = sbound[wib];
    const int E1 = sbound[wib + 1];

    const bool active = lane < batch;
    const float* xrow = x + (size_t)(active ? lane : 0) * (size_t)n_in;
    float*       orow = out + (size_t)lane * (size_t)n_out;

    const bool rowAligned = ((n_in & 3) == 0) && ((((uintptr_t)x) & 15) == 0);

    float acc = 0.f;
    int o_cur = o_begin;

#define FLUSH_TO(OE)                                            \
    while (o_cur < (OE)) {                                      \
        if (active) orow[o_cur] = tanhf(acc + bias[o_cur]);     \
        acc = 0.f; ++o_cur;                                     \
    }

#define EDGE_SCALAR(E)                                          \
    {                                                           \
        int oe_ = out_idx[(E)];                                 \
        if (oe_ != o_cur) { FLUSH_TO(oe_); }                    \
        acc = fmaf(xrow[in_idx[(E)]], wgt[(E)], acc);           \
    }

    // Head: scalar until e is 16B-aligned for the int4/float4 metadata loads.
    while (e < E1 && (e & 3)) { EDGE_SCALAR(e); ++e; }

    // Main: 4 edges per iteration.
    while (e + 4 <= E1) {
        int4   iv = *reinterpret_cast<const int4*>(in_idx + e);
        int4   ov = *reinterpret_cast<const int4*>(out_idx + e);
        float4 wv = *reinterpret_cast<const float4*>(wgt + e);
        const bool consec = rowAligned &
                            (iv.y == iv.x + 1) & (iv.z == iv.x + 2) &
                            (iv.w == iv.x + 3) & ((iv.x & 3) == 0);
        if (consec) {
            float4 xv = *reinterpret_cast<const float4*>(xrow + iv.x);
            if (ov.w == o_cur) {
                // whole group inside current segment (common case)
                acc = fmaf(xv.x, wv.x, acc);
                acc = fmaf(xv.y, wv.y, acc);
                acc = fmaf(xv.z, wv.z, acc);
                acc = fmaf(xv.w, wv.w, acc);
            } else {
                if (ov.x != o_cur) { FLUSH_TO(ov.x); }
                acc = fmaf(xv.x, wv.x, acc);
                if (ov.y != o_cur) { FLUSH_TO(ov.y); }
                acc = fmaf(xv.y, wv.y, acc);
                if (ov.z != o_cur) { FLUSH_TO(ov.z); }
                acc = fmaf(xv.z, wv.z, acc);
                if (ov.w != o_cur) { FLUSH_TO(ov.w); }
                acc = fmaf(xv.w, wv.w, acc);
            }
        } else {
            EDGE_SCALAR(e); EDGE_SCALAR(e + 1); EDGE_SCALAR(e + 2); EDGE_SCALAR(e + 3);
        }
        e += 4;
    }

    // Tail edges.
    while (e < E1) { EDGE_SCALAR(e); ++e; }

    // Flush remaining outputs in this wave's range (handles empty segments too).
    FLUSH_TO(o_end);

#undef EDGE_SCALAR
#undef FLUSH_TO
}

extern "C" void kernel_launch(void* const* d_in, const int* in_sizes, int n_in_arrs,
                              void* d_out, int out_size, void* d_ws, size_t ws_size,
                              hipStream_t stream)
{
    const float* x       = (const float*)d_in[0];
    const float* wgt     = (const float*)d_in[1];
    const float* bias    = (const float*)d_in[2];
    const int*   in_idx  = (const int*)d_in[3];
    const int*   out_idx = (const int*)d_in[4];
    float*       out     = (float*)d_out;

    const int nnz   = in_sizes[1];
    const int n_out = in_sizes[2];           // bias elements = N_OUT * FILTERS(=1)
    const int batch = out_size / n_out;      // 64
    const int n_in  = in_sizes[0] / batch;   // 1,000,000

    const int waves  = (n_out + OPW - 1) / OPW;
    const int blocks = (waves + WAVES_PER_BLOCK - 1) / WAVES_PER_BLOCK;

    hipLaunchKernelGGL(LocallyDirected1D_kernel, dim3(blocks), dim3(256), 0, stream,
                       x, wgt, bias, in_idx, out_idx, out,
                       n_in, nnz, n_out, batch);
}

// Round 2
// 159.049 us; speedup vs baseline: 1.7284x; 1.7284x over previous
//
#include <hip/hip_runtime.h>
#include <cstdint>
#include <cstddef>

// LocallyDirected1D: y[b,o] = tanh( sum_{e: out_idx[e]==o} x[b, in_idx[e]] * w[e] + bias[o] )
// out_idx sorted ascending; in_idx == arange in practice (verified per chunk, with
// global-gather fallback). lane <-> batch (B == 64 == wave size).
//
// Block = 4 waves owns OPB=16 consecutive outputs -> one contiguous edge range.
// x columns for that range are staged chunk-by-chunk (CK=128 cols) into a 64-row
// LDS tile via fully coalesced float4 reads; metadata (out_idx, w) staged too.
// Consumption is LDS-only. Results staged in LDS res tile, written out as float4.

constexpr int WPB = 4;              // waves per block
constexpr int OPW = 4;              // outputs per wave
constexpr int OPB = WPB * OPW;      // outputs per block = 16
constexpr int CK = 128;             // x columns per chunk
constexpr int PITCH = CK + 1;       // odd pitch -> conflict-free transposed reads
constexpr int RPITCH = OPB + 1;

__global__ __launch_bounds__(256)
void LocallyDirected1D_kernel(const float* __restrict__ x,
                              const float* __restrict__ wgt,
                              const float* __restrict__ bias,
                              const int*   __restrict__ in_idx,
                              const int*   __restrict__ out_idx,
                              float*       __restrict__ out,
                              int n_in, int nnz, int n_out, int batch)
{
    __shared__ float tile[64 * PITCH];
    __shared__ float res[64 * RPITCH];
    __shared__ alignas(16) int   s_oidx[CK];
    __shared__ alignas(16) float s_w[CK];
    __shared__ int sbound[WPB + 1];

    const int tid  = threadIdx.x;
    const int lane = tid & 63;
    const int wib  = tid >> 6;
    const int O0   = blockIdx.x * OPB;

    // Parallel lower_bound for the 5 wave-range boundaries.
    if (tid <= WPB) {
        int ob = min(O0 + tid * OPW, n_out);
        int lo = 0, hi = nnz;
        while (lo < hi) { int m = (lo + hi) >> 1; if (out_idx[m] < ob) lo = m + 1; else hi = m; }
        sbound[tid] = lo;
    }
    __syncthreads();

    const int B0 = sbound[0];
    const int B1 = sbound[WPB];
    const int CBASE = B0 & ~3;
    const int CEND  = min(nnz, (B1 + 3) & ~3);

    int e        = sbound[wib];
    const int E1 = sbound[wib + 1];
    int o_cur       = min(O0 + wib * OPW, n_out);
    const int o_end = min(o_cur + OPW, n_out);
    float acc = 0.f;
    const float* xrow = x + (size_t)min(lane, batch - 1) * (size_t)n_in;

#define FLUSH_TO(OE)                                                            \
    while (o_cur < (OE)) {                                                      \
        res[lane * RPITCH + (o_cur - O0)] = tanhf(acc + bias[o_cur]);           \
        acc = 0.f; ++o_cur;                                                     \
    }

    const int f0 = tid & 31;   // float4-column within chunk
    const int r0 = tid >> 5;   // row group 0..7

    for (int c0 = CBASE; c0 < CEND; c0 += CK) {
        const int s1  = min(c0 + CK, CEND);
        const int cnt = s1 - c0;           // multiple of 4
        const int nf4 = cnt >> 2;

        __syncthreads();                    // previous chunk fully consumed

        // Stage metadata + identity check on in_idx.
        int myok = 1;
        for (int idx = tid; idx < nf4; idx += 256) {
            const int base = c0 + idx * 4;
            int4 iv = *reinterpret_cast<const int4*>(in_idx + base);
            if (iv.x != base || iv.y != base + 1 || iv.z != base + 2 || iv.w != base + 3)
                myok = 0;
            int4   ov = *reinterpret_cast<const int4*>(out_idx + base);
            float4 wv = *reinterpret_cast<const float4*>(wgt + base);
            *reinterpret_cast<int4*>(s_oidx + idx * 4)   = ov;
            *reinterpret_cast<float4*>(s_w + idx * 4)    = wv;
        }

        // Stage x tile: coalesced float4 row reads -> padded LDS rows.
        if (f0 < nf4) {
            const int c = c0 + f0 * 4;
            if (c + 4 <= n_in) {
                for (int r = r0; r < 64; r += 8) {
                    float4 v = *reinterpret_cast<const float4*>(
                        x + (size_t)min(r, batch - 1) * (size_t)n_in + c);
                    float* dst = &tile[r * PITCH + f0 * 4];
                    dst[0] = v.x; dst[1] = v.y; dst[2] = v.z; dst[3] = v.w;
                }
            } else {
                for (int r = r0; r < 64; r += 8) {
                    const float* src = x + (size_t)min(r, batch - 1) * (size_t)n_in;
                    float* dst = &tile[r * PITCH + f0 * 4];
                    for (int j = 0; j < 4; ++j) dst[j] = (c + j < n_in) ? src[c + j] : 0.f;
                }
            }
        }

        const int ok  = __syncthreads_and(myok);
        const int lim = min(E1, s1);
        const int tb  = lane * PITCH - c0;  // tile[tb + e] == x[lane][e] when ok
        const int mb  = -c0;                // s_oidx[mb + e], s_w[mb + e]

        if (ok) {
            while (e < lim && (e & 3)) {
                int oe = s_oidx[mb + e];
                if (oe != o_cur) { FLUSH_TO(oe); }
                acc = fmaf(tile[tb + e], s_w[mb + e], acc);
                ++e;
            }
            while (e + 4 <= lim) {
                int4   ov = *reinterpret_cast<const int4*>(s_oidx + (mb + e));
                float4 wv = *reinterpret_cast<const float4*>(s_w + (mb + e));
                const int t0 = tb + e;
                if (ov.w == o_cur) {
                    acc = fmaf(tile[t0 + 0], wv.x, acc);
                    acc = fmaf(tile[t0 + 1], wv.y, acc);
                    acc = fmaf(tile[t0 + 2], wv.z, acc);
                    acc = fmaf(tile[t0 + 3], wv.w, acc);
                } else {
                    if (ov.x != o_cur) { FLUSH_TO(ov.x); }
                    acc = fmaf(tile[t0 + 0], wv.x, acc);
                    if (ov.y != o_cur) { FLUSH_TO(ov.y); }
                    acc = fmaf(tile[t0 + 1], wv.y, acc);
                    if (ov.z != o_cur) { FLUSH_TO(ov.z); }
                    acc = fmaf(tile[t0 + 2], wv.z, acc);
                    if (ov.w != o_cur) { FLUSH_TO(ov.w); }
                    acc = fmaf(tile[t0 + 3], wv.w, acc);
                }
                e += 4;
            }
            while (e < lim) {
                int oe = s_oidx[mb + e];
                if (oe != o_cur) { FLUSH_TO(oe); }
                acc = fmaf(tile[tb + e], s_w[mb + e], acc);
                ++e;
            }
        } else {
            // Fallback: gather x from global (in_idx not identity in this chunk).
            while (e < lim) {
                int oe = s_oidx[mb + e];
                if (oe != o_cur) { FLUSH_TO(oe); }
                acc = fmaf(xrow[in_idx[e]], s_w[mb + e], acc);
                ++e;
            }
        }
    }

    // Finish remaining outputs in this wave's range (covers empty segments).
    FLUSH_TO(o_end);
#undef FLUSH_TO

    __syncthreads();

    // Coalesced writeout from res tile.
    const int nO = min(OPB, n_out - O0);
    if (nO == OPB && (n_out & 3) == 0) {
        const int b = tid >> 2, k = tid & 3;   // 256 threads = 64 rows x 4 float4s
        if (b < batch) {
            const float* rp = &res[b * RPITCH + k * 4];
            float4 v = make_float4(rp[0], rp[1], rp[2], rp[3]);
            *reinterpret_cast<float4*>(out + (size_t)b * n_out + O0 + k * 4) = v;
        }
    } else {
        for (int idx = tid; idx < batch * nO; idx += 256) {
            int b = idx / nO, k = idx - b * nO;
            out[(size_t)b * n_out + O0 + k] = res[b * RPITCH + k];
        }
    }
}

extern "C" void kernel_launch(void* const* d_in, const int* in_sizes, int n_in_arrs,
                              void* d_out, int out_size, void* d_ws, size_t ws_size,
                              hipStream_t stream)
{
    const float* x       = (const float*)d_in[0];
    const float* wgt     = (const float*)d_in[1];
    const float* bias    = (const float*)d_in[2];
    const int*   in_idx  = (const int*)d_in[3];
    const int*   out_idx = (const int*)d_in[4];
    float*       out     = (float*)d_out;

    const int nnz   = in_sizes[1];
    const int n_out = in_sizes[2];           // bias elements = N_OUT * FILTERS(=1)
    const int batch = out_size / n_out;      // 64
    const int n_in  = in_sizes[0] / batch;   // 1,000,000

    const int blocks = (n_out + OPB - 1) / OPB;

    hipLaunchKernelGGL(LocallyDirected1D_kernel, dim3(blocks), dim3(256), 0, stream,
                       x, wgt, bias, in_idx, out_idx, out,
                       n_in, nnz, n_out, batch);
}

// Round 3
// 80.896 us; speedup vs baseline: 3.3981x; 1.9661x over previous
//
#include <hip/hip_runtime.h>
#include <cstdint>
#include <cstddef>

// LocallyDirected1D: y[b,o] = tanh( sum_{e: out_idx[e]==o} x[b, in_idx[e]] * w[e] + bias[o] )
// out_idx sorted ascending; in_idx == arange in practice (verified per window, wave-uniform
// gather fallback otherwise).
//
// R3 design: lane = edge-quad (64 lanes x 4 edges = 256-edge window per wave), loop over
// batch rows. Per row: one coalesced float4 load of x[b][c0+4*lane .. +3], products, and a
// DPP-only masked segmented scan (masks precomputed once per window -- run structure is
// row-independent). Run-end lanes emit segment sums via fp32 atomics into pre (= d_out,
// zeroed by a prologue kernel); a final kernel applies bias + tanh in place.
// No LDS, no __syncthreads, zero bank conflicts.

constexpr int EPW = 256;   // edges per window
constexpr int RPW = 32;    // batch rows per wave (2 waves share a window)
constexpr int WPB = 4;     // waves per block (256 threads)

#define DPP_SHR1 0x111
#define DPP_SHR2 0x112
#define DPP_SHR4 0x114
#define DPP_SHR8 0x118
#define DPP_BC15 0x142
#define DPP_BC31 0x143

// s += mask * dpp_shift(s); bound_ctrl=true -> invalid source reads 0; old=0 -> untargeted rows 0.
#define SCAN_STEP(S, MF, CTRL, RM)                                                            \
    {                                                                                         \
        int _t = __builtin_amdgcn_update_dpp(0, __float_as_int(S), (CTRL), (RM), 0xF, true);  \
        (S) = fmaf((MF), __int_as_float(_t), (S));                                            \
    }

#define MAXS_STEP(R, CTRL, RM)                                                                \
    {                                                                                         \
        int _t = __builtin_amdgcn_update_dpp(0, (R), (CTRL), (RM), 0xF, true);                \
        (R) = max((R), _t);                                                                   \
    }

__device__ __forceinline__ void atomAddF(float* p, float v) {
    __hip_atomic_fetch_add(p, v, __ATOMIC_RELAXED, __HIP_MEMORY_SCOPE_AGENT);
}

__global__ __launch_bounds__(256)
void ld1d_zero(float* __restrict__ p, int n4, int ntot)
{
    int i = blockIdx.x * 256 + threadIdx.x;
    if (i < n4)
        *reinterpret_cast<float4*>(p + (size_t)i * 4) = make_float4(0.f, 0.f, 0.f, 0.f);
    if (blockIdx.x == 0 && threadIdx.x == 0)
        for (int k = n4 * 4; k < ntot; ++k) p[k] = 0.f;
}

__global__ __launch_bounds__(256)
void ld1d_accum(const float* __restrict__ x, const float* __restrict__ wgt,
                const int* __restrict__ in_idx, const int* __restrict__ out_idx,
                float* __restrict__ pre, int n_in, int nnz, int n_out, int batch, int wpw)
{
    const int lane = threadIdx.x & 63;
    const int gw   = blockIdx.x * WPB + (threadIdx.x >> 6);
    const int wid  = gw / wpw;
    const long long c0l = (long long)wid * EPW;
    if (c0l >= (long long)nnz) return;
    const int c0 = (int)c0l;
    const int b0 = (gw - wid * wpw) * RPW;
    const int nrows = min(RPW, batch - b0);
    if (nrows <= 0) return;

    const int e0   = c0 + lane * 4;
    const bool vq  = (e0 + 3 < nnz);   // whole quad valid
    const bool anyv = (e0 < nnz);
    const int last = nnz - 1;

    int4 iv; int4 ov; float4 wv;
    bool fastok;
    if (vq) {
        iv = *reinterpret_cast<const int4*>(in_idx + e0);
        ov = *reinterpret_cast<const int4*>(out_idx + e0);
        wv = *reinterpret_cast<const float4*>(wgt + e0);
        fastok = (iv.x == e0) && (iv.y == e0 + 1) && (iv.z == e0 + 2) && (iv.w == e0 + 3);
    } else if (anyv) {
        int ei0 = min(e0 + 0, last), ei1 = min(e0 + 1, last),
            ei2 = min(e0 + 2, last), ei3 = min(e0 + 3, last);
        iv = make_int4(in_idx[ei0], in_idx[ei1], in_idx[ei2], in_idx[ei3]);
        ov = make_int4(out_idx[ei0], out_idx[ei1], out_idx[ei2], out_idx[ei3]);
        wv = make_float4(e0 + 0 < nnz ? wgt[ei0] : 0.f, e0 + 1 < nnz ? wgt[ei1] : 0.f,
                         e0 + 2 < nnz ? wgt[ei2] : 0.f, e0 + 3 < nnz ? wgt[ei3] : 0.f);
        fastok = false;                // partial quad -> force gather path (rare)
    } else {
        int o = out_idx[last];
        iv = make_int4(0, 0, 0, 0);
        ov = make_int4(o, o, o, o);    // joins final run with zero weight
        wv = make_float4(0.f, 0.f, 0.f, 0.f);
        fastok = true;
    }
    const bool fast = (bool)__all((int)fastok);

    // Clamped indices for both paths.
    const int nmax = n_in - 1;
    const int ix0 = min(max(iv.x, 0), nmax), ix1 = min(max(iv.y, 0), nmax);
    const int ix2 = min(max(iv.z, 0), nmax), ix3 = min(max(iv.w, 0), nmax);
    const int ex0 = min(max(e0, 0), max(n_in - 4, 0));

    // Run structure (row-independent, computed once).
    const bool b01 = ov.x != ov.y, b12 = ov.y != ov.z, b23 = ov.z != ov.w;
    const bool hasB = b01 || b12 || b23;
    const int  prevw = __shfl_up(ov.w, 1);
    const bool cont  = (lane > 0) && (ov.x == prevw);
    const bool fbrk  = hasB || !cont;              // scan restarts at this lane
    const int  fnext = __shfl_down((int)fbrk, 1);
    const bool Eend  = (lane == 63) || (fnext != 0);  // tail-run ends at this lane

    // tail masks (edge k belongs to e3's run), head masks (edge k belongs to e0's run)
    const float tm2 = b23 ? 0.f : 1.f;
    const float tm1 = (b23 || b12) ? 0.f : 1.f;
    const float tm0 = (b23 || b12 || b01) ? 0.f : 1.f;
    const float hm1 = b01 ? 0.f : 1.f;
    const float hm2 = (b01 || b12) ? 0.f : 1.f;
    const float hm3 = (b01 || b12 || b23) ? 0.f : 1.f;
    // mid runs (wholly inside the lane)
    const bool  hasM1 = b01 && (b12 || b23);       // run starting at e1 -> ov.y
    const bool  hasM2 = b12 && b23;                // run {e2} -> ov.z
    const float mw    = b12 ? 0.f : 1.f;           // mid1 = q1 + mw*q2
    const bool  anyMid  = (bool)__any((int)(hasM1 || hasM2));
    const bool  anyHead = (bool)__any((int)hasB);

    // r = run-start lane via unsegmented DPP max-scan of (fbrk ? lane : 0)
    int r = fbrk ? lane : 0;
    MAXS_STEP(r, DPP_SHR1, 0xF); MAXS_STEP(r, DPP_SHR2, 0xF);
    MAXS_STEP(r, DPP_SHR4, 0xF); MAXS_STEP(r, DPP_SHR8, 0xF);
    MAXS_STEP(r, DPP_BC15, 0xA); MAXS_STEP(r, DPP_BC31, 0xC);

    // Per-step scan masks: add source lane iff it lies in the same run.
    const float mf1  = (r <= lane - 1) ? 1.f : 0.f;
    const float mf2  = (r <= lane - 2) ? 1.f : 0.f;
    const float mf4  = (r <= lane - 4) ? 1.f : 0.f;
    const float mf8  = (r <= lane - 8) ? 1.f : 0.f;
    const float mf15 = (r <= (lane & ~15) - 1) ? 1.f : 0.f;   // src 15 / 47
    const float mf31 = (r <= 31) ? 1.f : 0.f;                 // src 31

    const float* xp = x + (size_t)b0 * (size_t)n_in;
    float*       pb = pre + (size_t)b0 * (size_t)n_out;

    #pragma unroll 4
    for (int i = 0; i < nrows; ++i) {
        float q0, q1, q2, q3;
        if (fast) {
            float4 xv = *reinterpret_cast<const float4*>(xp + ex0);
            q0 = xv.x * wv.x; q1 = xv.y * wv.y; q2 = xv.z * wv.z; q3 = xv.w * wv.w;
        } else {
            q0 = xp[ix0] * wv.x; q1 = xp[ix1] * wv.y;
            q2 = xp[ix2] * wv.z; q3 = xp[ix3] * wv.w;
        }
        // scan input: this lane's tail-run sum
        float s = q3; s = fmaf(tm2, q2, s); s = fmaf(tm1, q1, s); s = fmaf(tm0, q0, s);
        SCAN_STEP(s, mf1,  DPP_SHR1, 0xF);
        SCAN_STEP(s, mf2,  DPP_SHR2, 0xF);
        SCAN_STEP(s, mf4,  DPP_SHR4, 0xF);
        SCAN_STEP(s, mf8,  DPP_SHR8, 0xF);
        SCAN_STEP(s, mf15, DPP_BC15, 0xA);
        SCAN_STEP(s, mf31, DPP_BC31, 0xC);
        if (Eend) atomAddF(pb + ov.w, s);          // tail-run total for run ending here
        if (anyHead) {
            float h = q0; h = fmaf(hm1, q1, h); h = fmaf(hm2, q2, h); h = fmaf(hm3, q3, h);
            if (hasB) atomAddF(pb + ov.x, h);      // head part (left part emitted by lane-1's Eend)
        }
        if (anyMid) {
            if (hasM1) atomAddF(pb + ov.y, fmaf(mw, q2, q1));
            if (hasM2) atomAddF(pb + ov.z, q2);
        }
        xp += n_in; pb += n_out;
    }
}

__global__ __launch_bounds__(256)
void ld1d_finish_vec(float* __restrict__ out, const float* __restrict__ bias, int n_out4)
{
    const int o4 = blockIdx.x * 256 + threadIdx.x;
    if (o4 >= n_out4) return;
    const size_t flat = (size_t)blockIdx.y * (size_t)n_out4 * 4 + (size_t)o4 * 4;
    float4 v  = *reinterpret_cast<float4*>(out + flat);
    float4 bz = *reinterpret_cast<const float4*>(bias + (size_t)o4 * 4);
    v.x = tanhf(v.x + bz.x); v.y = tanhf(v.y + bz.y);
    v.z = tanhf(v.z + bz.z); v.w = tanhf(v.w + bz.w);
    *reinterpret_cast<float4*>(out + flat) = v;
}

__global__ __launch_bounds__(256)
void ld1d_finish_scalar(float* __restrict__ out, const float* __restrict__ bias,
                        int n_out, int ntot)
{
    int i = blockIdx.x * 256 + threadIdx.x;
    if (i >= ntot) return;
    int o = i % n_out;
    out[i] = tanhf(out[i] + bias[o]);
}

extern "C" void kernel_launch(void* const* d_in, const int* in_sizes, int n_in_arrs,
                              void* d_out, int out_size, void* d_ws, size_t ws_size,
                              hipStream_t stream)
{
    const float* x       = (const float*)d_in[0];
    const float* wgt     = (const float*)d_in[1];
    const float* bias    = (const float*)d_in[2];
    const int*   in_idx  = (const int*)d_in[3];
    const int*   out_idx = (const int*)d_in[4];
    float*       out     = (float*)d_out;

    const int nnz   = in_sizes[1];
    const int n_out = in_sizes[2];           // N_OUT * FILTERS(=1)
    const int batch = out_size / n_out;      // 64
    const int n_in  = in_sizes[0] / batch;   // 1,000,000

    // Z: zero the accumulator (= d_out)
    const int n4 = out_size / 4;
    hipLaunchKernelGGL(ld1d_zero, dim3((n4 + 255) / 256), dim3(256), 0, stream,
                       out, n4, out_size);

    // A: edge-window accumulate with DPP segmented scan + atomics
    const int nwin = (nnz + EPW - 1) / EPW;
    const int wpw  = (batch + RPW - 1) / RPW;              // waves per window
    const long long totalWaves = (long long)nwin * wpw;
    const int ablocks = (int)((totalWaves + WPB - 1) / WPB);
    hipLaunchKernelGGL(ld1d_accum, dim3(ablocks), dim3(256), 0, stream,
                       x, wgt, in_idx, out_idx, out, n_in, nnz, n_out, batch, wpw);

    // B: bias + tanh in place
    if ((n_out & 3) == 0) {
        const int n_out4 = n_out / 4;
        hipLaunchKernelGGL(ld1d_finish_vec,
                           dim3((n_out4 + 255) / 256, batch), dim3(256), 0, stream,
                           out, bias, n_out4);
    } else {
        hipLaunchKernelGGL(ld1d_finish_scalar,
                           dim3((out_size + 255) / 256), dim3(256), 0, stream,
                           out, bias, n_out, out_size);
    }
}